// Round 1
// 6092.038 us; speedup vs baseline: 1.6862x; 1.6862x over previous
//
#include <hip/hip_runtime.h>
#include <math.h>

// ---------------------------------------------------------------------------
// Qwen2.5-Vision block on MI355X — round 3: full-bf16 GEMM path.
// Weights pre-converted fp32->bf16 per use; GEMM uses global_load_lds (16B)
// with inverse-swizzled global source + XOR-swizzled ds_read_b128 (m97/m173
// pattern), 128x128 tile, BK=64. Attention unchanged except bf16 output.
// ---------------------------------------------------------------------------

#define N_TOK 2304

typedef __bf16 bf16x8 __attribute__((ext_vector_type(8)));
typedef float floatx4 __attribute__((ext_vector_type(4)));

// perm-order block id for final-order block j  (win[j])
__device__ __forceinline__ int win_of(int j) {
    int iw  = j & 3;
    int ih  = (j >> 2) & 3;
    int gwo = (j >> 4) % 6;
    int go  = j / 96;
    return (go * 4 + ih) * 24 + (gwo * 4 + iw);
}

// raw (perm-order) token -> final-order token
__device__ __forceinline__ int dstrow_patch(int r) {
    int w4   = r & 3;
    int jraw = r >> 2;
    int gh = jraw / 24, gw = jraw % 24;
    int go = gh >> 2, ih = gh & 3, gwo = gw >> 2, iw = gw & 3;
    int b = ((go * 6 + gwo) * 4 + ih) * 4 + iw;
    return b * 4 + w4;
}

// async 16B global -> LDS (wave-uniform LDS base + lane*16 dest)
__device__ __forceinline__ void gload16(const __bf16* g, __bf16* l) {
    __builtin_amdgcn_global_load_lds(
        (const __attribute__((address_space(1))) void*)g,
        (__attribute__((address_space(3))) void*)l, 16, 0, 0);
}

// ---------------------------------------------------------------------------
// bf16 MFMA GEMM:  C[m][n] = epi( A[m][:].B[n][:] + bias[n] + resid )
// A (M x K) bf16 row-major, B (N x K) bf16 row-major. fp32 accumulate.
// 128x128 tile, BK=64, 256 thr (4 waves 2x2), wave = 64x64 out.
// K must be a multiple of 64 (callers pad). M/N tails: clamped loads +
// masked stores.  LDS layout: linear [128][64] bf16, data placed with
// granule swizzle g -> g ^ (row&7) via pre-swizzled GLOBAL source address;
// ds_read_b128 applies the same XOR -> conflict-free fragment reads.
// act: 0=none, 1=exact gelu.  mulgate: v = silu(mulgate)*v (stride ldaux).
// resid stride ldaux. rowmap: 0 none, 1 patch scatter, 2 win scatter.
// npad: store zeros for N <= gn < npad (zero-fills padded K columns of the
// next GEMM's A). cbf16: output dtype (0 fp32, 1 bf16).
// ---------------------------------------------------------------------------
#define BM 128
#define BN 128
#define BKG 64

__global__ __launch_bounds__(256) void gemm_bf16(
    const __bf16* __restrict__ A, int lda,
    const __bf16* __restrict__ B, int ldb,
    const float* __restrict__ bias,
    const float* __restrict__ resid,
    const float* __restrict__ mulgate, int ldaux,
    void* __restrict__ Cout, int ldc,
    int M, int N, int npad, int K, int act, int rowmap, int cbf16)
{
    __shared__ __bf16 As[BM * BKG];   // 16 KB
    __shared__ __bf16 Bs[BN * BKG];   // 16 KB

    const int tid  = threadIdx.x;
    const int lane = tid & 63;
    const int w    = tid >> 6;
    const int wm = w & 1, wn = w >> 1;
    const int l15 = lane & 15, lq = lane >> 4;
    const int x0 = blockIdx.x * BN, y0 = blockIdx.y * BM;

    // ---- staging geometry -------------------------------------------------
    // instruction q = w*4+it covers rows [q*8, q*8+8); lane l -> row q*8+(l>>3),
    // LDS granule (l&7). Source granule pre-swizzled: (l&7) ^ (row&7), and
    // row&7 == l>>3 here, so it is lane-constant across the 4 issues.
    const int sgx = (((lane & 7) ^ (lane >> 3)) << 3);   // element offset in BK tile
    const int sr0 = (w << 5) + (lane >> 3);              // + it*8

    size_t arow[4], brow[4];
#pragma unroll
    for (int it = 0; it < 4; it++) {
        int rA = y0 + sr0 + it * 8; if (rA > M - 1) rA = M - 1;  // clamp: garbage
        int rB = x0 + sr0 + it * 8; if (rB > N - 1) rB = N - 1;  // rows are masked
        arow[it] = (size_t)rA * lda;
        brow[it] = (size_t)rB * ldb;
    }
    __bf16* asb = &As[(w << 2) * 512];   // + it*512 elems (it*1024 B)
    __bf16* bsb = &Bs[(w << 2) * 512];

    floatx4 acc[4][4] = {};

    for (int k0 = 0; k0 < K; k0 += BKG) {
#pragma unroll
        for (int it = 0; it < 4; it++) {
            gload16(A + arow[it] + k0 + sgx, asb + it * 512);
            gload16(B + brow[it] + k0 + sgx, bsb + it * 512);
        }
        __syncthreads();   // compiler drains vmcnt before s_barrier

#pragma unroll
        for (int kk = 0; kk < 2; kk++) {
            bf16x8 af[4], bv[4];
#pragma unroll
            for (int i = 0; i < 4; i++) {
                int r = (wm << 6) + (i << 4) + l15;
                int g = (kk << 2) | lq;
                af[i] = *(const bf16x8*)&As[(r << 6) + ((g ^ (r & 7)) << 3)];
            }
#pragma unroll
            for (int j = 0; j < 4; j++) {
                int r = (wn << 6) + (j << 4) + l15;
                int g = (kk << 2) | lq;
                bv[j] = *(const bf16x8*)&Bs[(r << 6) + ((g ^ (r & 7)) << 3)];
            }
#pragma unroll
            for (int i = 0; i < 4; i++)
#pragma unroll
                for (int j = 0; j < 4; j++)
                    acc[i][j] = __builtin_amdgcn_mfma_f32_16x16x32_bf16(
                        af[i], bv[j], acc[i][j], 0, 0, 0);
        }
        __syncthreads();
    }

    // ---- epilogue ---------------------------------------------------------
#pragma unroll
    for (int i = 0; i < 4; i++) {
#pragma unroll
        for (int r = 0; r < 4; r++) {
            int gm = y0 + (wm << 6) + (i << 4) + (lq << 2) + r;
            if (gm >= M) continue;
            int orow = gm;
            if (rowmap == 1) orow = dstrow_patch(gm);
            else if (rowmap == 2) orow = win_of(gm);
#pragma unroll
            for (int j = 0; j < 4; j++) {
                int gn = x0 + (wn << 6) + (j << 4) + l15;
                if (gn >= npad) continue;
                float v = 0.f;
                if (gn < N) {
                    v = acc[i][j][r];
                    if (bias) v += bias[gn];
                    if (resid) v += resid[(size_t)gm * ldaux + gn];
                    if (mulgate) {
                        float g = mulgate[(size_t)gm * ldaux + gn];
                        v = g / (1.f + __expf(-g)) * v;
                    }
                    if (act == 1) v = 0.5f * v * (1.f + erff(v * 0.70710678118654752f));
                }
                if (cbf16) ((__bf16*)Cout)[(size_t)orow * ldc + gn] = (__bf16)v;
                else       ((float*)Cout)[(size_t)orow * ldc + gn] = v;
            }
        }
    }
}

// ---------------------------------------------------------------------------
// fp32 -> bf16 conversion, 8 elems/thread (n must be a multiple of 8).
// ---------------------------------------------------------------------------
__global__ __launch_bounds__(256) void cvt_bf16_k(const float* __restrict__ src,
                                                  __bf16* __restrict__ dst, long n)
{
    long i = ((long)blockIdx.x * 256 + threadIdx.x) * 8;
    if (i >= n) return;
    float4 a = *(const float4*)(src + i);
    float4 b = *(const float4*)(src + i + 4);
    bf16x8 o = { (__bf16)a.x, (__bf16)a.y, (__bf16)a.z, (__bf16)a.w,
                 (__bf16)b.x, (__bf16)b.y, (__bf16)b.z, (__bf16)b.w };
    *(bf16x8*)(dst + i) = o;
}

// fp32 (rows x K) -> bf16 (rows x ldd), zero-padding cols K..ldd-1.
__global__ __launch_bounds__(256) void cvt_pad_k(const float* __restrict__ src,
                                                 __bf16* __restrict__ dst,
                                                 int rows, int K, int ldd)
{
    int idx = blockIdx.x * 256 + threadIdx.x;
    int perrow = ldd >> 3;
    int row = idx / perrow;
    if (row >= rows) return;
    int c8 = (idx - row * perrow) << 3;
    __bf16 o[8];
#pragma unroll
    for (int u = 0; u < 8; u++) {
        int c = c8 + u;
        o[u] = (__bf16)(c < K ? src[(size_t)row * K + c] : 0.f);
    }
    *(bf16x8*)(dst + (size_t)row * ldd + c8) = *(bf16x8*)o;
}

// ---------------------------------------------------------------------------
// RMSNorm over last dim 1280, bf16 output.  grid = rows, block = 256.
// ---------------------------------------------------------------------------
__global__ __launch_bounds__(256) void rmsnorm_k(const float* __restrict__ x,
                                                 const float* __restrict__ w,
                                                 __bf16* __restrict__ out)
{
    int row = blockIdx.x, tid = threadIdx.x;
    const float* xr = x + (size_t)row * 1280;
    float ss = 0.f;
#pragma unroll
    for (int it = 0; it < 5; it++) { float v = xr[tid + it * 256]; ss += v * v; }
#pragma unroll
    for (int o = 32; o > 0; o >>= 1) ss += __shfl_xor(ss, o);
    __shared__ float wsum[4];
    if ((tid & 63) == 0) wsum[tid >> 6] = ss;
    __syncthreads();
    float tot = wsum[0] + wsum[1] + wsum[2] + wsum[3];
    float sc = rsqrtf(tot * (1.f / 1280.f) + 1e-6f);
#pragma unroll
    for (int it = 0; it < 5; it++) {
        int i = tid + it * 256;
        out[(size_t)row * 1280 + i] = (__bf16)(xr[i] * sc * w[i]);
    }
}

// ---------------------------------------------------------------------------
// RoPE in-place on qkv (S, 3*1280): rotates q and k. grid = tokens.
// ---------------------------------------------------------------------------
__global__ __launch_bounds__(256) void rope_k(float* __restrict__ qkv)
{
    int f = blockIdx.x;
    int b = f >> 2, w4 = f & 3;
    int wb = win_of(b);
    float hpos = (float)(2 * (wb / 24) + (w4 >> 1));
    float wpos = (float)(2 * (wb % 24) + (w4 & 1));
    for (int t = threadIdx.x; t < 640; t += 256) {
        int head = t / 40, d = t % 40;
        int i = d % 20;
        float invf = powf(10000.f, -(float)i * (1.f / 20.f));
        float ang = (d < 20 ? hpos : wpos) * invf;
        float c = cosf(ang), s = sinf(ang);
        float* qp = qkv + (size_t)f * 3840 + head * 80;
        float* kp = qp + 1280;
        float q0 = qp[d], q1 = qp[d + 40];
        qp[d]      = q0 * c - q1 * s;
        qp[d + 40] = q1 * c + q0 * s;
        float k0 = kp[d], k1 = kp[d + 40];
        kp[d]      = k0 * c - k1 * s;
        kp[d + 40] = k1 * c + k0 * s;
    }
}

// ---------------------------------------------------------------------------
// Attention: one block = (q-tile of 64 rows, head). Online softmax over K-tiles.
// bf16 output (feeds proj GEMM A-operand).
// ---------------------------------------------------------------------------
__global__ __launch_bounds__(256) void attn_k(const float* __restrict__ qkv,
                                              __bf16* __restrict__ out, int full)
{
    int qt = blockIdx.x, head = blockIdx.y;
    __shared__ float Ks[64 * 84];
    __shared__ float Vs[64 * 80];
    __shared__ float Ps[64 * 65];
    int tid = threadIdx.x;
    int row = tid >> 2, cgrp = tid & 3;

    float4 qreg[20];
    const float4* qp = (const float4*)(qkv + (size_t)(qt * 64 + row) * 3840 + head * 80);
#pragma unroll
    for (int d = 0; d < 20; d++) qreg[d] = qp[d];

    float oc[20];
#pragma unroll
    for (int c = 0; c < 20; c++) oc[c] = 0.f;
    float m_i = -1e30f, l_i = 0.f;

    int kt0 = full ? 0 : qt, kte = full ? 36 : qt + 1;
    for (int kt = kt0; kt < kte; kt++) {
        __syncthreads();
        for (int i = tid; i < 64 * 20; i += 256) {
            int r = i / 20, d4 = i % 20;
            const float4* kg = (const float4*)(qkv + (size_t)(kt * 64 + r) * 3840 + 1280 + head * 80);
            const float4* vg = (const float4*)(qkv + (size_t)(kt * 64 + r) * 3840 + 2560 + head * 80);
            ((float4*)&Ks[r * 84])[d4] = kg[d4];
            ((float4*)&Vs[r * 80])[d4] = vg[d4];
        }
        __syncthreads();

        float sc[16];
        float tmax = -1e30f;
#pragma unroll
        for (int c = 0; c < 16; c++) {
            int col = cgrp + 4 * c;
            const float4* kp = (const float4*)&Ks[col * 84];
            float acc = 0.f;
#pragma unroll
            for (int d = 0; d < 20; d++) {
                float4 k4 = kp[d];
                acc += qreg[d].x * k4.x + qreg[d].y * k4.y + qreg[d].z * k4.z + qreg[d].w * k4.w;
            }
            sc[c] = acc * 0.11180339887498949f; // 80^-0.5
            tmax = fmaxf(tmax, sc[c]);
        }
        tmax = fmaxf(tmax, __shfl_xor(tmax, 1));
        tmax = fmaxf(tmax, __shfl_xor(tmax, 2));
        float mnew  = fmaxf(m_i, tmax);
        float alpha = __expf(m_i - mnew);
        float psum = 0.f;
#pragma unroll
        for (int c = 0; c < 16; c++) {
            float p = __expf(sc[c] - mnew);
            Ps[row * 65 + cgrp + 4 * c] = p;
            psum += p;
        }
        psum += __shfl_xor(psum, 1);
        psum += __shfl_xor(psum, 2);
        l_i = l_i * alpha + psum;
        m_i = mnew;
#pragma unroll
        for (int c = 0; c < 20; c++) oc[c] *= alpha;
        __syncthreads();

        for (int k = 0; k < 64; k++) {
            float p = Ps[row * 65 + k];
            const float4* vp = (const float4*)&Vs[k * 80 + cgrp * 20];
#pragma unroll
            for (int c4 = 0; c4 < 5; c4++) {
                float4 v4 = vp[c4];
                oc[c4 * 4 + 0] += p * v4.x;
                oc[c4 * 4 + 1] += p * v4.y;
                oc[c4 * 4 + 2] += p * v4.z;
                oc[c4 * 4 + 3] += p * v4.w;
            }
        }
    }

    float inv_l = 1.f / l_i;
    __bf16* op = out + (size_t)(qt * 64 + row) * 1280 + head * 80 + cgrp * 20;
#pragma unroll
    for (int c = 0; c < 20; c++) op[c] = (__bf16)(oc[c] * inv_l);
}

// ---------------------------------------------------------------------------
extern "C" void kernel_launch(void* const* d_in, const int* in_sizes, int n_in,
                              void* d_out, int out_size, void* d_ws, size_t ws_size,
                              hipStream_t stream)
{
    (void)in_sizes; (void)n_in; (void)out_size; (void)ws_size;
    const float* pixel   = (const float*)d_in[0];
    const float* patch_w = (const float*)d_in[1];
    const float* qkv_w   = (const float*)d_in[2];
    const float* qkv_b   = (const float*)d_in[3];
    const float* proj_w  = (const float*)d_in[4];
    const float* proj_b  = (const float*)d_in[5];
    const float* norm1_w = (const float*)d_in[6];
    const float* norm2_w = (const float*)d_in[7];
    const float* gate_w  = (const float*)d_in[8];
    const float* gate_b  = (const float*)d_in[9];
    const float* up_w    = (const float*)d_in[10];
    const float* up_b    = (const float*)d_in[11];
    const float* down_w  = (const float*)d_in[12];
    const float* down_b  = (const float*)d_in[13];
    const float* ln_q_w  = (const float*)d_in[14];
    const float* m1_w    = (const float*)d_in[15];
    const float* m1_b    = (const float*)d_in[16];
    const float* m2_w    = (const float*)d_in[17];
    const float* m2_b    = (const float*)d_in[18];
    float* out = (float*)d_out;

    // workspace layout (bytes; all 16B-aligned)
    char* wsb = (char*)d_ws;
    float*  xbuf = (float*)(wsb);                    // 2304*1280 f32   11.80 MB
    float*  qkvb = (float*)(wsb + 11796480);         // 2304*3840 f32   35.39 MB
    float*  Gbuf = (float*)(wsb + 47185920);         // 2304*3420 f32   31.52 MB
    __bf16* hbuf = (__bf16*)(wsb + 78704640);        // 2304*1280 bf16   5.90 MB
    __bf16* Ubuf = (__bf16*)(wsb + 84602880);        // 2304*3456 bf16  15.93 MB
    __bf16* Wl   = (__bf16*)(wsb + 100528128);       // <=26.22M bf16   52.43 MB
    __bf16* pixb = Wl + 1556480;                     // 2304*1216 bf16 (after patch_w)
    // total: ~153 MB

    auto cvt = [&](const float* s, __bf16* d, long n) {
        cvt_bf16_k<<<dim3((unsigned)((n / 8 + 255) / 256)), dim3(256), 0, stream>>>(s, d, n);
    };
    auto cvtpad = [&](const float* s, __bf16* d, int rows, int K, int ldd) {
        long thr = (long)rows * (ldd / 8);
        cvt_pad_k<<<dim3((unsigned)((thr + 255) / 256)), dim3(256), 0, stream>>>(s, d, rows, K, ldd);
    };
    auto gemm = [&](const __bf16* A, int lda, const __bf16* B, int ldb,
                    const float* bias, const float* resid, const float* mg, int ldaux,
                    void* C, int ldc, int M, int N, int npad, int K,
                    int act, int rowmap, int cbf) {
        dim3 g((N + BN - 1) / BN, (M + BM - 1) / BM);
        gemm_bf16<<<g, dim3(256), 0, stream>>>(A, lda, B, ldb, bias, resid, mg, ldaux,
                                               C, ldc, M, N, npad, K, act, rowmap, cbf);
    };

    // patch embed (K 1176 padded to 1216), scattered into final token order
    cvtpad(patch_w, Wl, 1280, 1176, 1216);
    cvtpad(pixel, pixb, 2304, 1176, 1216);
    gemm(pixb, 1216, Wl, 1216, nullptr, nullptr, nullptr, 0,
         xbuf, 1280, N_TOK, 1280, 1280, 1216, 0, 1, 0);

    for (int i = 0; i < 8; i++) {
        int full = (i == 3 || i == 7) ? 1 : 0;

        rmsnorm_k<<<N_TOK, 256, 0, stream>>>(xbuf, norm1_w + i * 1280, hbuf);
        cvt(qkv_w + (size_t)i * 3840 * 1280, Wl, 3840L * 1280);
        gemm(hbuf, 1280, Wl, 1280, qkv_b + (size_t)i * 3840, nullptr, nullptr, 0,
             qkvb, 3840, N_TOK, 3840, 3840, 1280, 0, 0, 0);
        rope_k<<<N_TOK, 256, 0, stream>>>(qkvb);
        attn_k<<<dim3(36, 16), dim3(256), 0, stream>>>(qkvb, hbuf, full);
        cvt(proj_w + (size_t)i * 1280 * 1280, Wl, 1280L * 1280);
        gemm(hbuf, 1280, Wl, 1280, proj_b + (size_t)i * 1280, xbuf, nullptr, 1280,
             xbuf, 1280, N_TOK, 1280, 1280, 1280, 0, 0, 0);

        rmsnorm_k<<<N_TOK, 256, 0, stream>>>(xbuf, norm2_w + i * 1280, hbuf);
        cvt(gate_w + (size_t)i * 3420 * 1280, Wl, 3420L * 1280);
        gemm(hbuf, 1280, Wl, 1280, gate_b + (size_t)i * 3420, nullptr, nullptr, 0,
             Gbuf, 3420, N_TOK, 3420, 3420, 1280, 0, 0, 0);
        cvt(up_w + (size_t)i * 3420 * 1280, Wl, 3420L * 1280);
        // up GEMM with fused silu(gate)*up, bf16 out into K-padded Ubuf
        gemm(hbuf, 1280, Wl, 1280, up_b + (size_t)i * 3420, nullptr, Gbuf, 3420,
             Ubuf, 3456, N_TOK, 3420, 3456, 1280, 0, 0, 1);
        cvtpad(down_w + (size_t)i * 1280 * 3420, Wl, 1280, 3420, 3456);
        gemm(Ubuf, 3456, Wl, 3456, down_b + (size_t)i * 1280, xbuf, nullptr, 1280,
             xbuf, 1280, N_TOK, 1280, 1280, 3456, 0, 0, 0);
    }

    // final merger MLP: rmsnorm -> (576,5120) -> gelu(m1) -> m2 -> scatter rows
    rmsnorm_k<<<N_TOK, 256, 0, stream>>>(xbuf, ln_q_w, hbuf);
    cvt(m1_w, Wl, 5120L * 5120);
    gemm(hbuf, 5120, Wl, 5120, m1_b, nullptr, nullptr, 0,
         Ubuf, 5120, 576, 5120, 5120, 5120, 1, 0, 1);
    cvt(m2_w, Wl, 3584L * 5120);
    gemm(Ubuf, 5120, Wl, 5120, m2_b, nullptr, nullptr, 0,
         out, 3584, 576, 3584, 3584, 5120, 0, 2, 0);
}

// Round 2
// 4416.492 us; speedup vs baseline: 2.3259x; 1.3794x over previous
//
#include <hip/hip_runtime.h>
#include <math.h>

// ---------------------------------------------------------------------------
// Qwen2.5-Vision block on MI355X — round 4: MFMA flash attention.
// GEMM path unchanged from round 3 (bf16 weights, global_load_lds staging).
// New: qkv_pack_k (rope fused, bf16 Q/K padded + V transposed),
//      attn_mfma_k (flash attention, 16x16x32 bf16 MFMA, swizzled LDS).
// ---------------------------------------------------------------------------

#define N_TOK 2304

typedef __bf16 bf16x8 __attribute__((ext_vector_type(8)));
typedef float floatx4 __attribute__((ext_vector_type(4)));

// perm-order block id for final-order block j  (win[j])
__device__ __forceinline__ int win_of(int j) {
    int iw  = j & 3;
    int ih  = (j >> 2) & 3;
    int gwo = (j >> 4) % 6;
    int go  = j / 96;
    return (go * 4 + ih) * 24 + (gwo * 4 + iw);
}

// raw (perm-order) token -> final-order token
__device__ __forceinline__ int dstrow_patch(int r) {
    int w4   = r & 3;
    int jraw = r >> 2;
    int gh = jraw / 24, gw = jraw % 24;
    int go = gh >> 2, ih = gh & 3, gwo = gw >> 2, iw = gw & 3;
    int b = ((go * 6 + gwo) * 4 + ih) * 4 + iw;
    return b * 4 + w4;
}

// async 16B global -> LDS (wave-uniform LDS base + lane*16 dest)
__device__ __forceinline__ void gload16(const __bf16* g, __bf16* l) {
    __builtin_amdgcn_global_load_lds(
        (const __attribute__((address_space(1))) void*)g,
        (__attribute__((address_space(3))) void*)l, 16, 0, 0);
}

// ---------------------------------------------------------------------------
// bf16 MFMA GEMM (unchanged from round 3).
// ---------------------------------------------------------------------------
#define BM 128
#define BN 128
#define BKG 64

__global__ __launch_bounds__(256) void gemm_bf16(
    const __bf16* __restrict__ A, int lda,
    const __bf16* __restrict__ B, int ldb,
    const float* __restrict__ bias,
    const float* __restrict__ resid,
    const float* __restrict__ mulgate, int ldaux,
    void* __restrict__ Cout, int ldc,
    int M, int N, int npad, int K, int act, int rowmap, int cbf16)
{
    __shared__ __bf16 As[BM * BKG];
    __shared__ __bf16 Bs[BN * BKG];

    const int tid  = threadIdx.x;
    const int lane = tid & 63;
    const int w    = tid >> 6;
    const int wm = w & 1, wn = w >> 1;
    const int l15 = lane & 15, lq = lane >> 4;
    const int x0 = blockIdx.x * BN, y0 = blockIdx.y * BM;

    const int sgx = (((lane & 7) ^ (lane >> 3)) << 3);
    const int sr0 = (w << 5) + (lane >> 3);

    size_t arow[4], brow[4];
#pragma unroll
    for (int it = 0; it < 4; it++) {
        int rA = y0 + sr0 + it * 8; if (rA > M - 1) rA = M - 1;
        int rB = x0 + sr0 + it * 8; if (rB > N - 1) rB = N - 1;
        arow[it] = (size_t)rA * lda;
        brow[it] = (size_t)rB * ldb;
    }
    __bf16* asb = &As[(w << 2) * 512];
    __bf16* bsb = &Bs[(w << 2) * 512];

    floatx4 acc[4][4] = {};

    for (int k0 = 0; k0 < K; k0 += BKG) {
#pragma unroll
        for (int it = 0; it < 4; it++) {
            gload16(A + arow[it] + k0 + sgx, asb + it * 512);
            gload16(B + brow[it] + k0 + sgx, bsb + it * 512);
        }
        __syncthreads();

#pragma unroll
        for (int kk = 0; kk < 2; kk++) {
            bf16x8 af[4], bv[4];
#pragma unroll
            for (int i = 0; i < 4; i++) {
                int r = (wm << 6) + (i << 4) + l15;
                int g = (kk << 2) | lq;
                af[i] = *(const bf16x8*)&As[(r << 6) + ((g ^ (r & 7)) << 3)];
            }
#pragma unroll
            for (int j = 0; j < 4; j++) {
                int r = (wn << 6) + (j << 4) + l15;
                int g = (kk << 2) | lq;
                bv[j] = *(const bf16x8*)&Bs[(r << 6) + ((g ^ (r & 7)) << 3)];
            }
#pragma unroll
            for (int i = 0; i < 4; i++)
#pragma unroll
                for (int j = 0; j < 4; j++)
                    acc[i][j] = __builtin_amdgcn_mfma_f32_16x16x32_bf16(
                        af[i], bv[j], acc[i][j], 0, 0, 0);
        }
        __syncthreads();
    }

#pragma unroll
    for (int i = 0; i < 4; i++) {
#pragma unroll
        for (int r = 0; r < 4; r++) {
            int gm = y0 + (wm << 6) + (i << 4) + (lq << 2) + r;
            if (gm >= M) continue;
            int orow = gm;
            if (rowmap == 1) orow = dstrow_patch(gm);
            else if (rowmap == 2) orow = win_of(gm);
#pragma unroll
            for (int j = 0; j < 4; j++) {
                int gn = x0 + (wn << 6) + (j << 4) + l15;
                if (gn >= npad) continue;
                float v = 0.f;
                if (gn < N) {
                    v = acc[i][j][r];
                    if (bias) v += bias[gn];
                    if (resid) v += resid[(size_t)gm * ldaux + gn];
                    if (mulgate) {
                        float g = mulgate[(size_t)gm * ldaux + gn];
                        v = g / (1.f + __expf(-g)) * v;
                    }
                    if (act == 1) v = 0.5f * v * (1.f + erff(v * 0.70710678118654752f));
                }
                if (cbf16) ((__bf16*)Cout)[(size_t)orow * ldc + gn] = (__bf16)v;
                else       ((float*)Cout)[(size_t)orow * ldc + gn] = v;
            }
        }
    }
}

// ---------------------------------------------------------------------------
// fp32 -> bf16 conversion helpers (unchanged).
// ---------------------------------------------------------------------------
__global__ __launch_bounds__(256) void cvt_bf16_k(const float* __restrict__ src,
                                                  __bf16* __restrict__ dst, long n)
{
    long i = ((long)blockIdx.x * 256 + threadIdx.x) * 8;
    if (i >= n) return;
    float4 a = *(const float4*)(src + i);
    float4 b = *(const float4*)(src + i + 4);
    bf16x8 o = { (__bf16)a.x, (__bf16)a.y, (__bf16)a.z, (__bf16)a.w,
                 (__bf16)b.x, (__bf16)b.y, (__bf16)b.z, (__bf16)b.w };
    *(bf16x8*)(dst + i) = o;
}

__global__ __launch_bounds__(256) void cvt_pad_k(const float* __restrict__ src,
                                                 __bf16* __restrict__ dst,
                                                 int rows, int K, int ldd)
{
    int idx = blockIdx.x * 256 + threadIdx.x;
    int perrow = ldd >> 3;
    int row = idx / perrow;
    if (row >= rows) return;
    int c8 = (idx - row * perrow) << 3;
    __bf16 o[8];
#pragma unroll
    for (int u = 0; u < 8; u++) {
        int c = c8 + u;
        o[u] = (__bf16)(c < K ? src[(size_t)row * K + c] : 0.f);
    }
    *(bf16x8*)(dst + (size_t)row * ldd + c8) = *(bf16x8*)o;
}

// ---------------------------------------------------------------------------
// RMSNorm over last dim 1280, bf16 output (unchanged).
// ---------------------------------------------------------------------------
__global__ __launch_bounds__(256) void rmsnorm_k(const float* __restrict__ x,
                                                 const float* __restrict__ w,
                                                 __bf16* __restrict__ out)
{
    int row = blockIdx.x, tid = threadIdx.x;
    const float* xr = x + (size_t)row * 1280;
    float ss = 0.f;
#pragma unroll
    for (int it = 0; it < 5; it++) { float v = xr[tid + it * 256]; ss += v * v; }
#pragma unroll
    for (int o = 32; o > 0; o >>= 1) ss += __shfl_xor(ss, o);
    __shared__ float wsum[4];
    if ((tid & 63) == 0) wsum[tid >> 6] = ss;
    __syncthreads();
    float tot = wsum[0] + wsum[1] + wsum[2] + wsum[3];
    float sc = rsqrtf(tot * (1.f / 1280.f) + 1e-6f);
#pragma unroll
    for (int it = 0; it < 5; it++) {
        int i = tid + it * 256;
        out[(size_t)row * 1280 + i] = (__bf16)(xr[i] * sc * w[i]);
    }
}

// ---------------------------------------------------------------------------
// qkv pack: rope(q,k) -> bf16 Q/K [head][tok][128] (d 80..127 zero),
// V -> bf16 V^T [head][80][2304].  grid = (36 token-tiles, 16 heads).
// ---------------------------------------------------------------------------
__global__ __launch_bounds__(256) void qkv_pack_k(
    const float* __restrict__ qkv,   // [2304][3840]
    __bf16* __restrict__ qb,
    __bf16* __restrict__ kb,
    __bf16* __restrict__ vt)
{
    int kt = blockIdx.x, head = blockIdx.y;
    int tid = threadIdx.x;
    __shared__ float Vls[64 * 80];

    // stage V tile (fp32) into LDS for transpose
    for (int i = tid; i < 64 * 20; i += 256) {
        int r = i / 20, d4 = i % 20;
        const float4* vg = (const float4*)(qkv + (size_t)(kt * 64 + r) * 3840 + 2560 + head * 80);
        *(float4*)&Vls[r * 80 + d4 * 4] = vg[d4];
    }

    // rope q,k: 64 tokens x 5 octets (d = 0..39 pairs with d+40)
    for (int idx = tid; idx < 320; idx += 256) {
        int r = idx / 5, o = idx % 5;
        int tok = kt * 64 + r;
        int b = tok >> 2, w4 = tok & 3;
        int wb = win_of(b);
        float hpos = (float)(2 * (wb / 24) + (w4 >> 1));
        float wpos = (float)(2 * (wb % 24) + (w4 & 1));
        const float* qp = qkv + (size_t)tok * 3840 + head * 80;
        const float* kp = qp + 1280;
        float c[8], s[8];
#pragma unroll
        for (int u = 0; u < 8; u++) {
            int d = o * 8 + u;
            float invf = powf(10000.f, -(float)(d % 20) * (1.f / 20.f));
            float ang = (d < 20 ? hpos : wpos) * invf;
            c[u] = cosf(ang); s[u] = sinf(ang);
        }
        float qlo[8], qhi[8], klo[8], khi[8];
        *(float4*)&qlo[0] = *(const float4*)(qp + o * 8);
        *(float4*)&qlo[4] = *(const float4*)(qp + o * 8 + 4);
        *(float4*)&qhi[0] = *(const float4*)(qp + o * 8 + 40);
        *(float4*)&qhi[4] = *(const float4*)(qp + o * 8 + 44);
        *(float4*)&klo[0] = *(const float4*)(kp + o * 8);
        *(float4*)&klo[4] = *(const float4*)(kp + o * 8 + 4);
        *(float4*)&khi[0] = *(const float4*)(kp + o * 8 + 40);
        *(float4*)&khi[4] = *(const float4*)(kp + o * 8 + 44);
        bf16x8 v0, v1, v2, v3;
#pragma unroll
        for (int u = 0; u < 8; u++) {
            v0[u] = (__bf16)(qlo[u] * c[u] - qhi[u] * s[u]);
            v1[u] = (__bf16)(qhi[u] * c[u] + qlo[u] * s[u]);
            v2[u] = (__bf16)(klo[u] * c[u] - khi[u] * s[u]);
            v3[u] = (__bf16)(khi[u] * c[u] + klo[u] * s[u]);
        }
        __bf16* qo = qb + ((size_t)head * 2304 + tok) * 128;
        __bf16* ko = kb + ((size_t)head * 2304 + tok) * 128;
        *(bf16x8*)(qo + o * 8)      = v0;
        *(bf16x8*)(qo + 40 + o * 8) = v1;
        *(bf16x8*)(ko + o * 8)      = v2;
        *(bf16x8*)(ko + 40 + o * 8) = v3;
    }

    // zero pad d 80..127
    for (int idx = tid; idx < 64 * 6; idx += 256) {
        int r = idx / 6, o = idx % 6;
        int tok = kt * 64 + r;
        bf16x8 z = {};
        *(bf16x8*)(qb + ((size_t)head * 2304 + tok) * 128 + 80 + o * 8) = z;
        *(bf16x8*)(kb + ((size_t)head * 2304 + tok) * 128 + 80 + o * 8) = z;
    }
    __syncthreads();

    // write V^T rows (coalesced along tokens)
    for (int i = tid; i < 640; i += 256) {
        int d = i >> 3, oc = i & 7;
        bf16x8 vv;
#pragma unroll
        for (int u = 0; u < 8; u++) vv[u] = (__bf16)Vls[(oc * 8 + u) * 80 + d];
        *(bf16x8*)(vt + ((size_t)head * 80 + d) * 2304 + kt * 64 + oc * 8) = vv;
    }
}

// ---------------------------------------------------------------------------
// MFMA flash attention. Block = (64-q tile, head), 4 waves x 16 q-rows.
// K LDS [64][128] bf16 (256B rows, 16 granules), V^T LDS [80][64] (128B rows),
// P LDS [64][64] — all granule-XOR-swizzled (g ^= row&7).
// ---------------------------------------------------------------------------
__global__ __launch_bounds__(256) void attn_mfma_k(
    const __bf16* __restrict__ qb,   // [16][2304][128]
    const __bf16* __restrict__ kb,   // [16][2304][128]
    const __bf16* __restrict__ vt,   // [16][80][2304]
    __bf16* __restrict__ out,        // [2304][1280]
    int full)
{
    __shared__ __bf16 Ks[64 * 128];  // 16 KB
    __shared__ __bf16 Vs[80 * 64];   // 10 KB
    __shared__ __bf16 Ps[64 * 64];   // 8 KB

    const int qt = blockIdx.x, head = blockIdx.y;
    const int tid = threadIdx.x;
    const int lane = tid & 63, w = tid >> 6;
    const int l15 = lane & 15, lq = lane >> 4;
    const float scale = 0.11180339887498949f;   // 80^-0.5

    // Q fragments for this wave's 16 rows (d padded with zeros to 96)
    const __bf16* qrow = qb + ((size_t)head * 2304 + qt * 64 + w * 16 + l15) * 128;
    bf16x8 aq[3];
#pragma unroll
    for (int ks = 0; ks < 3; ks++)
        aq[ks] = *(const bf16x8*)(qrow + ks * 32 + lq * 8);

    floatx4 oacc[5] = {};
    float m_i[4] = {-1e30f, -1e30f, -1e30f, -1e30f};
    float l_i[4] = {0.f, 0.f, 0.f, 0.f};

    const __bf16* kbase = kb + (size_t)head * 2304 * 128;
    const __bf16* vbase = vt + (size_t)head * 80 * 2304;

    const int kt0 = full ? 0 : qt, kte = full ? 36 : qt + 1;
    for (int kt = kt0; kt < kte; kt++) {
        // ---- stage K (1024 granules) + V^T (640 granules), swizzled source
        const __bf16* ksrc = kbase + (size_t)(kt * 64) * 128;
#pragma unroll
        for (int it = 0; it < 4; it++) {
            int G0 = (it * 4 + w) * 64;
            int row = (G0 + lane) >> 4;
            int gp = lane & 15;
            gload16(ksrc + row * 128 + ((gp ^ (row & 7)) << 3), &Ks[G0 * 8]);
        }
        for (int it = 0; it * 4 + w < 10; it++) {
            int G0 = (it * 4 + w) * 64;
            int row = (G0 + lane) >> 3;
            int gp = lane & 7;
            gload16(vbase + (size_t)row * 2304 + kt * 64 + ((gp ^ (row & 7)) << 3),
                    &Vs[G0 * 8]);
        }
        __syncthreads();

        // ---- S = Q K^T : wave computes 16 q-rows x 64 k-cols
        floatx4 sacc[4] = {};
        __builtin_amdgcn_s_setprio(1);
#pragma unroll
        for (int ks = 0; ks < 3; ks++)
#pragma unroll
            for (int j = 0; j < 4; j++) {
                int r = j * 16 + l15;
                bf16x8 bk = *(const bf16x8*)&Ks[r * 128 + (((ks * 4 + lq) ^ (r & 7)) << 3)];
                sacc[j] = __builtin_amdgcn_mfma_f32_16x16x32_bf16(aq[ks], bk, sacc[j], 0, 0, 0);
            }
        __builtin_amdgcn_s_setprio(0);

        // ---- online softmax; rows lq*4+rr; write P (bf16, swizzled)
        float alpha[4];
#pragma unroll
        for (int rr = 0; rr < 4; rr++) {
            float mx = fmaxf(fmaxf(sacc[0][rr], sacc[1][rr]),
                             fmaxf(sacc[2][rr], sacc[3][rr]));
#pragma unroll
            for (int msk = 1; msk < 16; msk <<= 1) mx = fmaxf(mx, __shfl_xor(mx, msk));
            float mnew = fmaxf(m_i[rr], mx * scale);
            alpha[rr] = __expf(m_i[rr] - mnew);
            m_i[rr] = mnew;
            int prow = w * 16 + lq * 4 + rr;
            float ps = 0.f;
#pragma unroll
            for (int j = 0; j < 4; j++) {
                float p = __expf(sacc[j][rr] * scale - mnew);
                ps += p;
                int gl = j * 2 + (l15 >> 3);
                Ps[prow * 64 + ((gl ^ (prow & 7)) << 3) + (l15 & 7)] = (__bf16)p;
            }
#pragma unroll
            for (int msk = 1; msk < 16; msk <<= 1) ps += __shfl_xor(ps, msk);
            l_i[rr] = l_i[rr] * alpha[rr] + ps;
        }
#pragma unroll
        for (int jo = 0; jo < 5; jo++)
#pragma unroll
            for (int rr = 0; rr < 4; rr++) oacc[jo][rr] *= alpha[rr];

        // ---- O += P V : wave computes 16 q-rows x 80 d
        const int prow_a = w * 16 + l15;
        __builtin_amdgcn_s_setprio(1);
#pragma unroll
        for (int ks = 0; ks < 2; ks++) {
            bf16x8 ap = *(const bf16x8*)&Ps[prow_a * 64 + (((ks * 4 + lq) ^ (prow_a & 7)) << 3)];
#pragma unroll
            for (int jo = 0; jo < 5; jo++) {
                int r = jo * 16 + l15;
                bf16x8 bv = *(const bf16x8*)&Vs[r * 64 + (((ks * 4 + lq) ^ (r & 7)) << 3)];
                oacc[jo] = __builtin_amdgcn_mfma_f32_16x16x32_bf16(ap, bv, oacc[jo], 0, 0, 0);
            }
        }
        __builtin_amdgcn_s_setprio(0);
        __syncthreads();
    }

    // ---- epilogue: O/l -> bf16 out
#pragma unroll
    for (int rr = 0; rr < 4; rr++) {
        float invl = 1.f / l_i[rr];
        size_t orow = (size_t)(qt * 64 + w * 16 + lq * 4 + rr) * 1280 + head * 80;
#pragma unroll
        for (int jo = 0; jo < 5; jo++)
            out[orow + jo * 16 + l15] = (__bf16)(oacc[jo][rr] * invl);
    }
}

// ---------------------------------------------------------------------------
extern "C" void kernel_launch(void* const* d_in, const int* in_sizes, int n_in,
                              void* d_out, int out_size, void* d_ws, size_t ws_size,
                              hipStream_t stream)
{
    (void)in_sizes; (void)n_in; (void)out_size; (void)ws_size;
    const float* pixel   = (const float*)d_in[0];
    const float* patch_w = (const float*)d_in[1];
    const float* qkv_w   = (const float*)d_in[2];
    const float* qkv_b   = (const float*)d_in[3];
    const float* proj_w  = (const float*)d_in[4];
    const float* proj_b  = (const float*)d_in[5];
    const float* norm1_w = (const float*)d_in[6];
    const float* norm2_w = (const float*)d_in[7];
    const float* gate_w  = (const float*)d_in[8];
    const float* gate_b  = (const float*)d_in[9];
    const float* up_w    = (const float*)d_in[10];
    const float* up_b    = (const float*)d_in[11];
    const float* down_w  = (const float*)d_in[12];
    const float* down_b  = (const float*)d_in[13];
    const float* ln_q_w  = (const float*)d_in[14];
    const float* m1_w    = (const float*)d_in[15];
    const float* m1_b    = (const float*)d_in[16];
    const float* m2_w    = (const float*)d_in[17];
    const float* m2_b    = (const float*)d_in[18];
    float* out = (float*)d_out;

    // workspace layout (bytes; all 16B-aligned)
    char* wsb = (char*)d_ws;
    float*  xbuf = (float*)(wsb);                    // 2304*1280 f32   11.80 MB
    float*  qkvb = (float*)(wsb + 11796480);         // 2304*3840 f32   35.39 MB
    float*  Gbuf = (float*)(wsb + 47185920);         // 2304*3420 f32   31.52 MB
    __bf16* hbuf = (__bf16*)(wsb + 78704640);        // 2304*1280 bf16   5.90 MB
    __bf16* Ubuf = (__bf16*)(wsb + 84602880);        // 2304*3456 bf16  15.93 MB
    __bf16* Wl   = (__bf16*)(wsb + 100528128);       // <=26.22M bf16   52.43 MB
    __bf16* pixb = Wl + 1556480;                     // 2304*1216 bf16
    // attention pack buffers alias Gbuf (lifetimes disjoint: pack/attn vs gate/up)
    __bf16* qbp = (__bf16*)Gbuf;                     // 16*2304*128 bf16  9.44 MB
    __bf16* kbp = qbp + (size_t)16 * 2304 * 128;     // 9.44 MB
    __bf16* vtp = kbp + (size_t)16 * 2304 * 128;     // 16*80*2304 bf16   5.90 MB

    auto cvt = [&](const float* s, __bf16* d, long n) {
        cvt_bf16_k<<<dim3((unsigned)((n / 8 + 255) / 256)), dim3(256), 0, stream>>>(s, d, n);
    };
    auto cvtpad = [&](const float* s, __bf16* d, int rows, int K, int ldd) {
        long thr = (long)rows * (ldd / 8);
        cvt_pad_k<<<dim3((unsigned)((thr + 255) / 256)), dim3(256), 0, stream>>>(s, d, rows, K, ldd);
    };
    auto gemm = [&](const __bf16* A, int lda, const __bf16* B, int ldb,
                    const float* bias, const float* resid, const float* mg, int ldaux,
                    void* C, int ldc, int M, int N, int npad, int K,
                    int act, int rowmap, int cbf) {
        dim3 g((N + BN - 1) / BN, (M + BM - 1) / BM);
        gemm_bf16<<<g, dim3(256), 0, stream>>>(A, lda, B, ldb, bias, resid, mg, ldaux,
                                               C, ldc, M, N, npad, K, act, rowmap, cbf);
    };

    // patch embed (K 1176 padded to 1216), scattered into final token order
    cvtpad(patch_w, Wl, 1280, 1176, 1216);
    cvtpad(pixel, pixb, 2304, 1176, 1216);
    gemm(pixb, 1216, Wl, 1216, nullptr, nullptr, nullptr, 0,
         xbuf, 1280, N_TOK, 1280, 1280, 1216, 0, 1, 0);

    for (int i = 0; i < 8; i++) {
        int full = (i == 3 || i == 7) ? 1 : 0;

        rmsnorm_k<<<N_TOK, 256, 0, stream>>>(xbuf, norm1_w + i * 1280, hbuf);
        cvt(qkv_w + (size_t)i * 3840 * 1280, Wl, 3840L * 1280);
        gemm(hbuf, 1280, Wl, 1280, qkv_b + (size_t)i * 3840, nullptr, nullptr, 0,
             qkvb, 3840, N_TOK, 3840, 3840, 1280, 0, 0, 0);
        qkv_pack_k<<<dim3(36, 16), dim3(256), 0, stream>>>(qkvb, qbp, kbp, vtp);
        attn_mfma_k<<<dim3(36, 16), dim3(256), 0, stream>>>(qbp, kbp, vtp, hbuf, full);
        cvt(proj_w + (size_t)i * 1280 * 1280, Wl, 1280L * 1280);
        gemm(hbuf, 1280, Wl, 1280, proj_b + (size_t)i * 1280, xbuf, nullptr, 1280,
             xbuf, 1280, N_TOK, 1280, 1280, 1280, 0, 0, 0);

        rmsnorm_k<<<N_TOK, 256, 0, stream>>>(xbuf, norm2_w + i * 1280, hbuf);
        cvt(gate_w + (size_t)i * 3420 * 1280, Wl, 3420L * 1280);
        gemm(hbuf, 1280, Wl, 1280, gate_b + (size_t)i * 3420, nullptr, nullptr, 0,
             Gbuf, 3420, N_TOK, 3420, 3420, 1280, 0, 0, 0);
        cvt(up_w + (size_t)i * 3420 * 1280, Wl, 3420L * 1280);
        gemm(hbuf, 1280, Wl, 1280, up_b + (size_t)i * 3420, nullptr, Gbuf, 3420,
             Ubuf, 3456, N_TOK, 3420, 3456, 1280, 0, 0, 1);
        cvtpad(down_w + (size_t)i * 1280 * 3420, Wl, 1280, 3420, 3456);
        gemm(Ubuf, 3456, Wl, 3456, down_b + (size_t)i * 1280, xbuf, nullptr, 1280,
             xbuf, 1280, N_TOK, 1280, 1280, 3456, 0, 0, 0);
    }

    // final merger MLP: rmsnorm -> (576,5120) -> gelu(m1) -> m2 -> scatter rows
    rmsnorm_k<<<N_TOK, 256, 0, stream>>>(xbuf, ln_q_w, hbuf);
    cvt(m1_w, Wl, 5120L * 5120);
    gemm(hbuf, 5120, Wl, 5120, m1_b, nullptr, nullptr, 0,
         Ubuf, 5120, 576, 5120, 5120, 5120, 1, 0, 1);
    cvt(m2_w, Wl, 3584L * 5120);
    gemm(Ubuf, 5120, Wl, 5120, m2_b, nullptr, nullptr, 0,
         out, 3584, 576, 3584, 3584, 5120, 0, 2, 0);
}